// Round 1
// baseline (1891.795 us; speedup 1.0000x reference)
//
#include <hip/hip_runtime.h>
#include <math.h>

#define N_NODES 50000
#define N_EDGES 800000
#define IN_FEAT 32
#define EDGE_FEAT 8
#define Z_DIM 72            // 2*IN_FEAT + EDGE_FEAT
#define HEADS 3
#define N_GRAPHS 64
#define E_SL (N_EDGES + N_NODES)   // GAT edges incl. self loops = 850000

static __device__ __forceinline__ float sigmoidf_(float x){ return 1.f/(1.f+__expf(-x)); }
// matches jax.nn.softplus = max(x,0)+log1p(exp(-|x|))
static __device__ __forceinline__ float softplusf_(float x){ return fmaxf(x,0.f) + log1pf(__expf(-fabsf(x))); }
static __device__ __forceinline__ float lrelu02(float x){ return x > 0.f ? x : 0.2f*x; }

// float atomic max via monotone integer-bit mapping (init must be -inf)
static __device__ __forceinline__ void atomicMaxF(float* a, float v){
    if (v >= 0.f) atomicMax((int*)a, __float_as_int(v));
    else          atomicMin((unsigned int*)a, (unsigned int)__float_as_int(v));
}

__global__ void k_fill(float* __restrict__ p, float v, int n){
    int i = blockIdx.x*blockDim.x + threadIdx.x;
    if (i < n) p[i] = v;
}

// o1 = relu(in); optionally o2 = relu(in) (accumulator init for next conv)
__global__ void k_relu2(const float* __restrict__ in, float* __restrict__ o1,
                        float* __restrict__ o2, int n){
    int i = blockIdx.x*blockDim.x + threadIdx.x;
    if (i < n){
        float r = fmaxf(in[i], 0.f);
        o1[i] = r;
        if (o2) o2[i] = r;
    }
}

// CGConv edge kernel: msg = sigmoid(z@Wf+bf) * softplus(z@Ws+bs), z=[x[dst],x[src],ea]
// acc must be pre-initialized to x (handles the "+x" residual); atomicAdd into acc[dst].
__global__ __launch_bounds__(256) void k_cgconv(
    const float* __restrict__ xin, float* __restrict__ acc,
    const float* __restrict__ ea,
    const int* __restrict__ srcv, const int* __restrict__ dstv,
    const float* __restrict__ Wf, const float* __restrict__ bf,
    const float* __restrict__ Ws, const float* __restrict__ bs)
{
    __shared__ float sWf[Z_DIM*IN_FEAT];   // 9 KB
    __shared__ float sWs[Z_DIM*IN_FEAT];   // 9 KB
    __shared__ float sz[8][Z_DIM];         // 8 edges per block-iteration
    for (int i = threadIdx.x; i < Z_DIM*IN_FEAT; i += 256){ sWf[i] = Wf[i]; sWs[i] = Ws[i]; }
    const int g = threadIdx.x >> 5;        // edge slot 0..7
    const int lane = threadIdx.x & 31;     // output channel 0..31
    const float bfl = bf[lane], bsl = bs[lane];
    __syncthreads();

    for (int base = blockIdx.x*8; base < N_EDGES; base += gridDim.x*8){
        int e = base + g;
        bool valid = e < N_EDGES;
        int s = 0, d = 0;
        if (valid){
            s = srcv[e]; d = dstv[e];
            sz[g][lane]      = xin[d*IN_FEAT + lane];   // x_i = x[dst]
            sz[g][32 + lane] = xin[s*IN_FEAT + lane];   // x_j = x[src]
            if (lane < EDGE_FEAT) sz[g][64 + lane] = ea[e*EDGE_FEAT + lane];
        }
        __syncthreads();
        if (valid){
            float af = bfl, as = bsl;
            #pragma unroll
            for (int k = 0; k < Z_DIM; k++){
                float zk = sz[g][k];
                af = fmaf(zk, sWf[k*IN_FEAT + lane], af);
                as = fmaf(zk, sWs[k*IN_FEAT + lane], as);
            }
            atomicAdd(&acc[d*IN_FEAT + lane], sigmoidf_(af)*softplusf_(as));
        }
        __syncthreads();
    }
}

// out[N][Co] = in[N][Ci] @ W[Ci][Co]   (no bias)
template<int Ci, int Co>
__global__ void k_linear(const float* __restrict__ in, const float* __restrict__ W,
                         float* __restrict__ out, int N){
    __shared__ float sW[Ci*Co];
    for (int i = threadIdx.x; i < Ci*Co; i += blockDim.x) sW[i] = W[i];
    __syncthreads();
    int idx = blockIdx.x*blockDim.x + threadIdx.x;
    if (idx >= N*Co) return;
    int n = idx / Co, co = idx % Co;
    const float* row = in + n*Ci;
    float a = 0.f;
    #pragma unroll
    for (int k = 0; k < Ci; k++) a = fmaf(row[k], sW[k*Co + co], a);
    out[idx] = a;
}

// attention logits per node: al[n][h] = sum_c hg[n][h][c] * a[h][c]
template<int C>
__global__ void k_al(const float* __restrict__ hg, const float* __restrict__ a_src,
                     const float* __restrict__ a_dst,
                     float* __restrict__ als, float* __restrict__ ald){
    int idx = blockIdx.x*blockDim.x + threadIdx.x;
    if (idx >= N_NODES*HEADS) return;
    int n = idx/HEADS, h = idx%HEADS;
    const float* row = hg + (n*HEADS + h)*C;
    float as = 0.f, ad = 0.f;
    #pragma unroll
    for (int c = 0; c < C; c++){
        float v = row[c];
        as = fmaf(v, a_src[h*C + c], as);
        ad = fmaf(v, a_dst[h*C + c], ad);
    }
    als[idx] = as; ald[idx] = ad;
}

static __device__ __forceinline__ void edge_sd(int e, const int* srcv, const int* dstv, int& s, int& d){
    if (e < N_EDGES){ s = srcv[e]; d = dstv[e]; }
    else            { s = e - N_EDGES; d = s; }   // self loops appended
}

__global__ void k_gat_max(const int* __restrict__ srcv, const int* __restrict__ dstv,
                          const float* __restrict__ als, const float* __restrict__ ald,
                          float* __restrict__ m){
    int idx = blockIdx.x*blockDim.x + threadIdx.x;
    if (idx >= E_SL*HEADS) return;
    int e = idx/HEADS, h = idx%HEADS;
    int s, d; edge_sd(e, srcv, dstv, s, d);
    float v = lrelu02(als[s*HEADS + h] + ald[d*HEADS + h]);
    atomicMaxF(&m[d*HEADS + h], v);
}

__global__ void k_gat_sum(const int* __restrict__ srcv, const int* __restrict__ dstv,
                          const float* __restrict__ als, const float* __restrict__ ald,
                          const float* __restrict__ m, float* __restrict__ P,
                          float* __restrict__ S){
    int idx = blockIdx.x*blockDim.x + threadIdx.x;
    if (idx >= E_SL*HEADS) return;
    int e = idx/HEADS, h = idx%HEADS;
    int s, d; edge_sd(e, srcv, dstv, s, d);
    float v = lrelu02(als[s*HEADS + h] + ald[d*HEADS + h]);
    float p = __expf(v - m[d*HEADS + h]);
    P[idx] = p;
    atomicAdd(&S[d*HEADS + h], p);
}

__global__ void k_gat_alpha(const int* __restrict__ dstv, const float* __restrict__ S,
                            float* __restrict__ P){
    int idx = blockIdx.x*blockDim.x + threadIdx.x;
    if (idx >= E_SL*HEADS) return;
    int e = idx/HEADS, h = idx%HEADS;
    int d = (e < N_EDGES) ? dstv[e] : (e - N_EDGES);
    P[idx] = P[idx] / (S[d*HEADS + h] + 1e-16f);
}

// O[dst][h][c] += hg[src][h][c] * alpha[e][h]
template<int C>
__global__ void k_gat_agg(const int* __restrict__ srcv, const int* __restrict__ dstv,
                          const float* __restrict__ hg, const float* __restrict__ P,
                          float* __restrict__ O){
    const int HC = HEADS*C;
    int idx = blockIdx.x*blockDim.x + threadIdx.x;
    if (idx >= E_SL*HC) return;
    int e = idx / HC, hc = idx % HC;
    int h = hc / C;
    int s, d; edge_sd(e, srcv, dstv, s, d);
    float alpha = P[e*HEADS + h];
    atomicAdd(&O[d*HC + hc], hg[s*HC + hc] * alpha);
}

template<int HC>
__global__ void k_bias_relu(float* __restrict__ O, const float* __restrict__ b){
    int idx = blockIdx.x*blockDim.x + threadIdx.x;
    if (idx >= N_NODES*HC) return;
    O[idx] = fmaxf(O[idx] + b[idx % HC], 0.f);
}

__global__ void k_pool(const float* __restrict__ O2, const int* __restrict__ batch,
                       float* __restrict__ sums, float* __restrict__ cnt){
    int idx = blockIdx.x*blockDim.x + threadIdx.x;
    if (idx >= N_NODES*48) return;
    int n = idx / 48, c = idx % 48;
    int b = batch[n];
    atomicAdd(&sums[b*48 + c], O2[idx]);
    if (c == 0) atomicAdd(&cnt[b], 1.f);
}

__global__ __launch_bounds__(1024) void k_mlp(
    const float* __restrict__ sums, const float* __restrict__ cnt,
    const float* __restrict__ Wl1, const float* __restrict__ bl1,
    const float* __restrict__ Wl2, const float* __restrict__ bl2,
    float* __restrict__ out){
    __shared__ float g[N_GRAPHS*48];
    __shared__ float g1[N_GRAPHS*16];
    int t = threadIdx.x;
    for (int i = t; i < N_GRAPHS*48; i += 1024) g[i] = sums[i] / fmaxf(cnt[i/48], 1.f);
    __syncthreads();
    if (t < N_GRAPHS*16){
        int n = t/16, j = t%16;
        float a = bl1[j];
        #pragma unroll
        for (int k = 0; k < 48; k++) a = fmaf(g[n*48 + k], Wl1[k*16 + j], a);
        g1[t] = fmaxf(a, 0.f);
    }
    __syncthreads();
    if (t < N_GRAPHS*10){
        int n = t/10, j = t%10;
        float a = bl2[j];
        #pragma unroll
        for (int k = 0; k < 16; k++) a = fmaf(g1[n*16 + k], Wl2[k*10 + j], a);
        out[n*10 + j] = a;
    }
}

extern "C" void kernel_launch(void* const* d_in, const int* in_sizes, int n_in,
                              void* d_out, int out_size, void* d_ws, size_t ws_size,
                              hipStream_t stream) {
    const float* x    = (const float*)d_in[0];
    const float* ea   = (const float*)d_in[1];
    const int*   ei   = (const int*)  d_in[2];
    const int*   batch= (const int*)  d_in[3];
    const float* Wf1 = (const float*)d_in[4];  const float* bf1 = (const float*)d_in[5];
    const float* Ws1 = (const float*)d_in[6];  const float* bs1 = (const float*)d_in[7];
    const float* Wf2 = (const float*)d_in[8];  const float* bf2 = (const float*)d_in[9];
    const float* Ws2 = (const float*)d_in[10]; const float* bs2 = (const float*)d_in[11];
    const float* Wg1 = (const float*)d_in[12];
    const float* asrc1=(const float*)d_in[13]; const float* adst1=(const float*)d_in[14];
    const float* bg1 = (const float*)d_in[15];
    const float* Wg2 = (const float*)d_in[16];
    const float* asrc2=(const float*)d_in[17]; const float* adst2=(const float*)d_in[18];
    const float* bg2 = (const float*)d_in[19];
    const float* Wl1 = (const float*)d_in[20]; const float* bl1 = (const float*)d_in[21];
    const float* Wl2 = (const float*)d_in[22]; const float* bl2 = (const float*)d_in[23];
    float* out = (float*)d_out;

    const int* srcv = ei;
    const int* dstv = ei + N_EDGES;

    // ---- workspace arena (floats); ~70.2 MB total, overlays by lifetime ----
    float* w   = (float*)d_ws;
    float* X0  = w;                 // 50000*32 = 1,600,000  (conv1 acc; later GAT1 input)
    float* X1  = X0 + 1600000;      // relu(conv1) = conv2 input
    float* X2  = X1 + 1600000;      // conv2 acc
    float* HG1 = X2 + 1600000;      // 50000*96 = 4,800,000
    float* O1  = HG1 + 4800000;     // 4,800,000
    float* P   = O1 + 4800000;      // 850000*3 = 2,550,000
    float* ALs = P + 2550000;       // 150,000
    float* ALd = ALs + 150000;      // 150,000
    float* M   = ALd + 150000;      // 150,000
    float* S   = M + 150000;        // 150,000
    float* POOL= S + 150000;        // 64*48 = 3072
    float* CNT = POOL + 3072;       // 64
    // overlays: HG1 is dead once GAT1 aggregation finishes
    float* HG2 = HG1;               // 50000*48 = 2,400,000
    float* O2  = HG1 + 2400000;     // 2,400,000
    (void)ws_size; (void)in_sizes; (void)n_in; (void)out_size;

    auto G = [](int n){ return (n + 255)/256; };

    // ---- CGConv 1 ----
    hipMemcpyAsync(X0, x, (size_t)1600000*sizeof(float), hipMemcpyDeviceToDevice, stream);
    k_cgconv<<<1280, 256, 0, stream>>>(x, X0, ea, srcv, dstv, Wf1, bf1, Ws1, bs1);
    k_relu2<<<G(1600000), 256, 0, stream>>>(X0, X1, X2, 1600000);   // X1 = input, X2 = acc init

    // ---- CGConv 2 ----
    k_cgconv<<<1280, 256, 0, stream>>>(X1, X2, ea, srcv, dstv, Wf2, bf2, Ws2, bs2);
    k_relu2<<<G(1600000), 256, 0, stream>>>(X2, X0, nullptr, 1600000); // X0 = GAT1 input

    // ---- GATConv 1 (C=32, HC=96) ----
    k_linear<32,96><<<G(N_NODES*96), 256, 0, stream>>>(X0, Wg1, HG1, N_NODES);
    k_al<32><<<G(N_NODES*HEADS), 256, 0, stream>>>(HG1, asrc1, adst1, ALs, ALd);
    k_fill<<<G(150000), 256, 0, stream>>>(M, -INFINITY, 150000);
    k_fill<<<G(150000), 256, 0, stream>>>(S, 0.f, 150000);
    k_fill<<<G(4800000), 256, 0, stream>>>(O1, 0.f, 4800000);
    k_gat_max<<<G(E_SL*HEADS), 256, 0, stream>>>(srcv, dstv, ALs, ALd, M);
    k_gat_sum<<<G(E_SL*HEADS), 256, 0, stream>>>(srcv, dstv, ALs, ALd, M, P, S);
    k_gat_alpha<<<G(E_SL*HEADS), 256, 0, stream>>>(dstv, S, P);
    k_gat_agg<32><<<G(E_SL*96), 256, 0, stream>>>(srcv, dstv, HG1, P, O1);
    k_bias_relu<96><<<G(N_NODES*96), 256, 0, stream>>>(O1, bg1);

    // ---- GATConv 2 (C=16, HC=48) ----
    k_linear<96,48><<<G(N_NODES*48), 256, 0, stream>>>(O1, Wg2, HG2, N_NODES);
    k_al<16><<<G(N_NODES*HEADS), 256, 0, stream>>>(HG2, asrc2, adst2, ALs, ALd);
    k_fill<<<G(150000), 256, 0, stream>>>(M, -INFINITY, 150000);
    k_fill<<<G(150000), 256, 0, stream>>>(S, 0.f, 150000);
    k_fill<<<G(2400000), 256, 0, stream>>>(O2, 0.f, 2400000);
    k_gat_max<<<G(E_SL*HEADS), 256, 0, stream>>>(srcv, dstv, ALs, ALd, M);
    k_gat_sum<<<G(E_SL*HEADS), 256, 0, stream>>>(srcv, dstv, ALs, ALd, M, P, S);
    k_gat_alpha<<<G(E_SL*HEADS), 256, 0, stream>>>(dstv, S, P);
    k_gat_agg<16><<<G(E_SL*48), 256, 0, stream>>>(srcv, dstv, HG2, P, O2);
    k_bias_relu<48><<<G(N_NODES*48), 256, 0, stream>>>(O2, bg2);

    // ---- pool + MLP ----
    k_fill<<<G(3136), 256, 0, stream>>>(POOL, 0.f, 3136);  // POOL + CNT contiguous
    k_pool<<<G(N_NODES*48), 256, 0, stream>>>(O2, batch, POOL, CNT);
    k_mlp<<<1, 1024, 0, stream>>>(POOL, CNT, Wl1, bl1, Wl2, bl2, out);
}

// Round 2
// 1574.433 us; speedup vs baseline: 1.2016x; 1.2016x over previous
//
#include <hip/hip_runtime.h>
#include <math.h>

#define N_NODES 50000
#define N_EDGES 800000
#define IN_FEAT 32
#define EDGE_FEAT 8
#define Z_DIM 72            // 2*IN_FEAT + EDGE_FEAT
#define HEADS 3
#define N_GRAPHS 64
#define E_SL (N_EDGES + N_NODES)   // GAT edges incl. self loops = 850000

static __device__ __forceinline__ float sigmoidf_(float x){ return 1.f/(1.f+__expf(-x)); }
// matches jax.nn.softplus = max(x,0)+log1p(exp(-|x|))
static __device__ __forceinline__ float softplusf_(float x){ return fmaxf(x,0.f) + log1pf(__expf(-fabsf(x))); }
static __device__ __forceinline__ float lrelu02(float x){ return x > 0.f ? x : 0.2f*x; }

// float atomic max via monotone integer-bit mapping (init must be -inf)
static __device__ __forceinline__ void atomicMaxF(float* a, float v){
    if (v >= 0.f) atomicMax((int*)a, __float_as_int(v));
    else          atomicMin((unsigned int*)a, (unsigned int)__float_as_int(v));
}

__global__ void k_fill(float* __restrict__ p, float v, int n){
    int i = blockIdx.x*blockDim.x + threadIdx.x;
    if (i < n) p[i] = v;
}

// o1 = relu(in); optionally o2 = relu(in) (accumulator init for next conv)
__global__ void k_relu2(const float* __restrict__ in, float* __restrict__ o1,
                        float* __restrict__ o2, int n){
    int i = blockIdx.x*blockDim.x + threadIdx.x;
    if (i < n){
        float r = fmaxf(in[i], 0.f);
        o1[i] = r;
        if (o2) o2[i] = r;
    }
}

// CGConv edge kernel: msg = sigmoid(z@Wf+bf) * softplus(z@Ws+bs), z=[x[dst],x[src],ea]
// acc must be pre-initialized to x (handles the "+x" residual); atomicAdd into acc[dst].
__global__ __launch_bounds__(256) void k_cgconv(
    const float* __restrict__ xin, float* __restrict__ acc,
    const float* __restrict__ ea,
    const int* __restrict__ srcv, const int* __restrict__ dstv,
    const float* __restrict__ Wf, const float* __restrict__ bf,
    const float* __restrict__ Ws, const float* __restrict__ bs)
{
    __shared__ float sWf[Z_DIM*IN_FEAT];   // 9 KB
    __shared__ float sWs[Z_DIM*IN_FEAT];   // 9 KB
    __shared__ float sz[8][Z_DIM];         // 8 edges per block-iteration
    for (int i = threadIdx.x; i < Z_DIM*IN_FEAT; i += 256){ sWf[i] = Wf[i]; sWs[i] = Ws[i]; }
    const int g = threadIdx.x >> 5;        // edge slot 0..7
    const int lane = threadIdx.x & 31;     // output channel 0..31
    const float bfl = bf[lane], bsl = bs[lane];
    __syncthreads();

    for (int base = blockIdx.x*8; base < N_EDGES; base += gridDim.x*8){
        int e = base + g;
        bool valid = e < N_EDGES;
        int s = 0, d = 0;
        if (valid){
            s = srcv[e]; d = dstv[e];
            sz[g][lane]      = xin[d*IN_FEAT + lane];   // x_i = x[dst]
            sz[g][32 + lane] = xin[s*IN_FEAT + lane];   // x_j = x[src]
            if (lane < EDGE_FEAT) sz[g][64 + lane] = ea[e*EDGE_FEAT + lane];
        }
        __syncthreads();
        if (valid){
            float af = bfl, as = bsl;
            #pragma unroll
            for (int k = 0; k < Z_DIM; k++){
                float zk = sz[g][k];
                af = fmaf(zk, sWf[k*IN_FEAT + lane], af);
                as = fmaf(zk, sWs[k*IN_FEAT + lane], as);
            }
            atomicAdd(&acc[d*IN_FEAT + lane], sigmoidf_(af)*softplusf_(as));
        }
        __syncthreads();
    }
}

// out[N][Co] = in[N][Ci] @ W[Ci][Co]   (no bias)
template<int Ci, int Co>
__global__ void k_linear(const float* __restrict__ in, const float* __restrict__ W,
                         float* __restrict__ out, int N){
    __shared__ float sW[Ci*Co];
    for (int i = threadIdx.x; i < Ci*Co; i += blockDim.x) sW[i] = W[i];
    __syncthreads();
    int idx = blockIdx.x*blockDim.x + threadIdx.x;
    if (idx >= N*Co) return;
    int n = idx / Co, co = idx % Co;
    const float* row = in + n*Ci;
    float a = 0.f;
    #pragma unroll
    for (int k = 0; k < Ci; k++) a = fmaf(row[k], sW[k*Co + co], a);
    out[idx] = a;
}

// attention logits per node: al[n][h] = sum_c hg[n][h][c] * a[h][c]
template<int C>
__global__ void k_al(const float* __restrict__ hg, const float* __restrict__ a_src,
                     const float* __restrict__ a_dst,
                     float* __restrict__ als, float* __restrict__ ald){
    int idx = blockIdx.x*blockDim.x + threadIdx.x;
    if (idx >= N_NODES*HEADS) return;
    int n = idx/HEADS, h = idx%HEADS;
    const float* row = hg + (n*HEADS + h)*C;
    float as = 0.f, ad = 0.f;
    #pragma unroll
    for (int c = 0; c < C; c++){
        float v = row[c];
        as = fmaf(v, a_src[h*C + c], as);
        ad = fmaf(v, a_dst[h*C + c], ad);
    }
    als[idx] = as; ald[idx] = ad;
}

static __device__ __forceinline__ void edge_sd(int e, const int* srcv, const int* dstv, int& s, int& d){
    if (e < N_EDGES){ s = srcv[e]; d = dstv[e]; }
    else            { s = e - N_EDGES; d = s; }   // self loops appended
}

__global__ void k_gat_max(const int* __restrict__ srcv, const int* __restrict__ dstv,
                          const float* __restrict__ als, const float* __restrict__ ald,
                          float* __restrict__ m){
    int idx = blockIdx.x*blockDim.x + threadIdx.x;
    if (idx >= E_SL*HEADS) return;
    int e = idx/HEADS, h = idx%HEADS;
    int s, d; edge_sd(e, srcv, dstv, s, d);
    float v = lrelu02(als[s*HEADS + h] + ald[d*HEADS + h]);
    atomicMaxF(&m[d*HEADS + h], v);
}

__global__ void k_gat_sum(const int* __restrict__ srcv, const int* __restrict__ dstv,
                          const float* __restrict__ als, const float* __restrict__ ald,
                          const float* __restrict__ m, float* __restrict__ P,
                          float* __restrict__ S){
    int idx = blockIdx.x*blockDim.x + threadIdx.x;
    if (idx >= E_SL*HEADS) return;
    int e = idx/HEADS, h = idx%HEADS;
    int s, d; edge_sd(e, srcv, dstv, s, d);
    float v = lrelu02(als[s*HEADS + h] + ald[d*HEADS + h]);
    float p = __expf(v - m[d*HEADS + h]);
    P[idx] = p;
    atomicAdd(&S[d*HEADS + h], p);
}

__global__ void k_gat_alpha(const int* __restrict__ dstv, const float* __restrict__ S,
                            float* __restrict__ P){
    int idx = blockIdx.x*blockDim.x + threadIdx.x;
    if (idx >= E_SL*HEADS) return;
    int e = idx/HEADS, h = idx%HEADS;
    int d = (e < N_EDGES) ? dstv[e] : (e - N_EDGES);
    P[idx] = P[idx] / (S[d*HEADS + h] + 1e-16f);
}

// O[dst][h][c] += hg[src][h][c] * alpha[e][h]
template<int C>
__global__ void k_gat_agg(const int* __restrict__ srcv, const int* __restrict__ dstv,
                          const float* __restrict__ hg, const float* __restrict__ P,
                          float* __restrict__ O){
    const int HC = HEADS*C;
    int idx = blockIdx.x*blockDim.x + threadIdx.x;
    if (idx >= E_SL*HC) return;
    int e = idx / HC, hc = idx % HC;
    int h = hc / C;
    int s, d; edge_sd(e, srcv, dstv, s, d);
    float alpha = P[e*HEADS + h];
    atomicAdd(&O[d*HC + hc], hg[s*HC + hc] * alpha);
}

template<int HC>
__global__ void k_bias_relu(float* __restrict__ O, const float* __restrict__ b){
    int idx = blockIdx.x*blockDim.x + threadIdx.x;
    if (idx >= N_NODES*HC) return;
    O[idx] = fmaxf(O[idx] + b[idx % HC], 0.f);
}

// One block per graph. batch is sorted, so graph g owns a contiguous node
// range found by binary search. 240 active threads = 48 channels x 5 node
// lanes; register-accumulate, LDS-reduce the 5 lanes, write the MEAN.
// No global atomics (replaces the 372us contention-bound k_pool).
__global__ __launch_bounds__(256) void k_pool2(
    const float* __restrict__ O2, const int* __restrict__ batch,
    float* __restrict__ gmean){
    __shared__ int s_range[2];
    __shared__ float red[240];
    const int gr = blockIdx.x;
    if (threadIdx.x < 2){
        int key = gr + threadIdx.x;           // lower_bound(batch, key)
        int lo = 0, hi = N_NODES;
        while (lo < hi){ int mid = (lo+hi) >> 1; if (batch[mid] < key) lo = mid+1; else hi = mid; }
        s_range[threadIdx.x] = lo;
    }
    __syncthreads();
    const int lo = s_range[0], hi = s_range[1];
    if (threadIdx.x < 240){
        const int c = threadIdx.x % 48, r = threadIdx.x / 48;
        float a = 0.f;
        for (int n = lo + r; n < hi; n += 5) a += O2[n*48 + c];
        red[threadIdx.x] = a;
    }
    __syncthreads();
    if (threadIdx.x < 48){
        float a = red[threadIdx.x] + red[48+threadIdx.x] + red[96+threadIdx.x]
                + red[144+threadIdx.x] + red[192+threadIdx.x];
        float cnt = (float)(hi - lo);
        gmean[gr*48 + threadIdx.x] = a / fmaxf(cnt, 1.f);
    }
}

__global__ __launch_bounds__(1024) void k_mlp(
    const float* __restrict__ g /* [64][48] graph means */,
    const float* __restrict__ Wl1, const float* __restrict__ bl1,
    const float* __restrict__ Wl2, const float* __restrict__ bl2,
    float* __restrict__ out){
    __shared__ float gs[N_GRAPHS*48];
    __shared__ float g1[N_GRAPHS*16];
    int t = threadIdx.x;
    for (int i = t; i < N_GRAPHS*48; i += 1024) gs[i] = g[i];
    __syncthreads();
    if (t < N_GRAPHS*16){
        int n = t/16, j = t%16;
        float a = bl1[j];
        #pragma unroll
        for (int k = 0; k < 48; k++) a = fmaf(gs[n*48 + k], Wl1[k*16 + j], a);
        g1[t] = fmaxf(a, 0.f);
    }
    __syncthreads();
    if (t < N_GRAPHS*10){
        int n = t/10, j = t%10;
        float a = bl2[j];
        #pragma unroll
        for (int k = 0; k < 16; k++) a = fmaf(g1[n*16 + k], Wl2[k*10 + j], a);
        out[n*10 + j] = a;
    }
}

extern "C" void kernel_launch(void* const* d_in, const int* in_sizes, int n_in,
                              void* d_out, int out_size, void* d_ws, size_t ws_size,
                              hipStream_t stream) {
    const float* x    = (const float*)d_in[0];
    const float* ea   = (const float*)d_in[1];
    const int*   ei   = (const int*)  d_in[2];
    const int*   batch= (const int*)  d_in[3];
    const float* Wf1 = (const float*)d_in[4];  const float* bf1 = (const float*)d_in[5];
    const float* Ws1 = (const float*)d_in[6];  const float* bs1 = (const float*)d_in[7];
    const float* Wf2 = (const float*)d_in[8];  const float* bf2 = (const float*)d_in[9];
    const float* Ws2 = (const float*)d_in[10]; const float* bs2 = (const float*)d_in[11];
    const float* Wg1 = (const float*)d_in[12];
    const float* asrc1=(const float*)d_in[13]; const float* adst1=(const float*)d_in[14];
    const float* bg1 = (const float*)d_in[15];
    const float* Wg2 = (const float*)d_in[16];
    const float* asrc2=(const float*)d_in[17]; const float* adst2=(const float*)d_in[18];
    const float* bg2 = (const float*)d_in[19];
    const float* Wl1 = (const float*)d_in[20]; const float* bl1 = (const float*)d_in[21];
    const float* Wl2 = (const float*)d_in[22]; const float* bl2 = (const float*)d_in[23];
    float* out = (float*)d_out;

    const int* srcv = ei;
    const int* dstv = ei + N_EDGES;

    // ---- workspace arena (floats); ~70.2 MB total, overlays by lifetime ----
    float* w   = (float*)d_ws;
    float* X0  = w;                 // 50000*32 = 1,600,000  (conv1 acc; later GAT1 input)
    float* X1  = X0 + 1600000;      // relu(conv1) = conv2 input
    float* X2  = X1 + 1600000;      // conv2 acc
    float* HG1 = X2 + 1600000;      // 50000*96 = 4,800,000
    float* O1  = HG1 + 4800000;     // 4,800,000
    float* P   = O1 + 4800000;      // 850000*3 = 2,550,000
    float* ALs = P + 2550000;       // 150,000
    float* ALd = ALs + 150000;      // 150,000
    float* M   = ALd + 150000;      // 150,000
    float* S   = M + 150000;        // 150,000
    float* GM  = S + 150000;        // 64*48 graph means
    // overlays: HG1 is dead once GAT1 aggregation finishes
    float* HG2 = HG1;               // 50000*48 = 2,400,000
    float* O2  = HG1 + 2400000;     // 2,400,000
    (void)ws_size; (void)in_sizes; (void)n_in; (void)out_size;

    auto G = [](int n){ return (n + 255)/256; };

    // ---- CGConv 1 ----
    hipMemcpyAsync(X0, x, (size_t)1600000*sizeof(float), hipMemcpyDeviceToDevice, stream);
    k_cgconv<<<1280, 256, 0, stream>>>(x, X0, ea, srcv, dstv, Wf1, bf1, Ws1, bs1);
    k_relu2<<<G(1600000), 256, 0, stream>>>(X0, X1, X2, 1600000);   // X1 = input, X2 = acc init

    // ---- CGConv 2 ----
    k_cgconv<<<1280, 256, 0, stream>>>(X1, X2, ea, srcv, dstv, Wf2, bf2, Ws2, bs2);
    k_relu2<<<G(1600000), 256, 0, stream>>>(X2, X0, nullptr, 1600000); // X0 = GAT1 input

    // ---- GATConv 1 (C=32, HC=96) ----
    k_linear<32,96><<<G(N_NODES*96), 256, 0, stream>>>(X0, Wg1, HG1, N_NODES);
    k_al<32><<<G(N_NODES*HEADS), 256, 0, stream>>>(HG1, asrc1, adst1, ALs, ALd);
    k_fill<<<G(150000), 256, 0, stream>>>(M, -INFINITY, 150000);
    k_fill<<<G(150000), 256, 0, stream>>>(S, 0.f, 150000);
    k_fill<<<G(4800000), 256, 0, stream>>>(O1, 0.f, 4800000);
    k_gat_max<<<G(E_SL*HEADS), 256, 0, stream>>>(srcv, dstv, ALs, ALd, M);
    k_gat_sum<<<G(E_SL*HEADS), 256, 0, stream>>>(srcv, dstv, ALs, ALd, M, P, S);
    k_gat_alpha<<<G(E_SL*HEADS), 256, 0, stream>>>(dstv, S, P);
    k_gat_agg<32><<<G(E_SL*96), 256, 0, stream>>>(srcv, dstv, HG1, P, O1);
    k_bias_relu<96><<<G(N_NODES*96), 256, 0, stream>>>(O1, bg1);

    // ---- GATConv 2 (C=16, HC=48) ----
    k_linear<96,48><<<G(N_NODES*48), 256, 0, stream>>>(O1, Wg2, HG2, N_NODES);
    k_al<16><<<G(N_NODES*HEADS), 256, 0, stream>>>(HG2, asrc2, adst2, ALs, ALd);
    k_fill<<<G(150000), 256, 0, stream>>>(M, -INFINITY, 150000);
    k_fill<<<G(150000), 256, 0, stream>>>(S, 0.f, 150000);
    k_fill<<<G(2400000), 256, 0, stream>>>(O2, 0.f, 2400000);
    k_gat_max<<<G(E_SL*HEADS), 256, 0, stream>>>(srcv, dstv, ALs, ALd, M);
    k_gat_sum<<<G(E_SL*HEADS), 256, 0, stream>>>(srcv, dstv, ALs, ALd, M, P, S);
    k_gat_alpha<<<G(E_SL*HEADS), 256, 0, stream>>>(dstv, S, P);
    k_gat_agg<16><<<G(E_SL*48), 256, 0, stream>>>(srcv, dstv, HG2, P, O2);
    k_bias_relu<48><<<G(N_NODES*48), 256, 0, stream>>>(O2, bg2);

    // ---- pool + MLP ----
    k_pool2<<<N_GRAPHS, 256, 0, stream>>>(O2, batch, GM);
    k_mlp<<<1, 1024, 0, stream>>>(GM, Wl1, bl1, Wl2, bl2, out);
}

// Round 3
// 1269.189 us; speedup vs baseline: 1.4906x; 1.2405x over previous
//
#include <hip/hip_runtime.h>
#include <math.h>

#define N_NODES 50000
#define N_EDGES 800000
#define IN_FEAT 32
#define EDGE_FEAT 8
#define Z_DIM 72            // 2*IN_FEAT + EDGE_FEAT
#define HEADS 3
#define N_GRAPHS 64
#define E_SL (N_EDGES + N_NODES)   // GAT edges incl. self loops = 850000

static __device__ __forceinline__ float sigmoidf_(float x){ return 1.f/(1.f+__expf(-x)); }
// matches jax.nn.softplus = max(x,0)+log1p(exp(-|x|))
static __device__ __forceinline__ float softplusf_(float x){ return fmaxf(x,0.f) + log1pf(__expf(-fabsf(x))); }
static __device__ __forceinline__ float lrelu02(float x){ return x > 0.f ? x : 0.2f*x; }

// float atomic max via monotone integer-bit mapping (init must be -inf)
static __device__ __forceinline__ void atomicMaxF(float* a, float v){
    if (v >= 0.f) atomicMax((int*)a, __float_as_int(v));
    else          atomicMin((unsigned int*)a, (unsigned int)__float_as_int(v));
}

__global__ void k_fill(float* __restrict__ p, float v, int n){
    int i = blockIdx.x*blockDim.x + threadIdx.x;
    if (i < n) p[i] = v;
}

// o1 = relu(in); optionally o2 = relu(in) (accumulator init for next conv)
__global__ void k_relu2(const float* __restrict__ in, float* __restrict__ o1,
                        float* __restrict__ o2, int n){
    int i = blockIdx.x*blockDim.x + threadIdx.x;
    if (i < n){
        float r = fmaxf(in[i], 0.f);
        o1[i] = r;
        if (o2) o2[i] = r;
    }
}

// CGConv precompute: AB[n][128] = [ x@Wf_dst + bf | x@Wf_src | x@Ws_dst + bs | x@Ws_src ]
// where W*_dst = rows 0..31, W*_src = rows 32..63 of the 72x32 weight.
// Converts the per-edge 72x32 matvec into per-edge table adds (4.5x FLOP cut).
__global__ __launch_bounds__(256) void k_pre(
    const float* __restrict__ x,
    const float* __restrict__ Wf, const float* __restrict__ bf,
    const float* __restrict__ Ws, const float* __restrict__ bs,
    float* __restrict__ AB)
{
    __shared__ float sC[32*128];   // sC[k][j] = weight multiplying x[n][k] for output j
    for (int i = threadIdx.x; i < 32*128; i += 256){
        int k = i >> 7, j = i & 127;
        float w;
        if      (j < 32)  w = Wf[k*32 + j];
        else if (j < 64)  w = Wf[(32+k)*32 + (j-32)];
        else if (j < 96)  w = Ws[k*32 + (j-64)];
        else              w = Ws[(32+k)*32 + (j-96)];
        sC[i] = w;
    }
    __syncthreads();
    int idx = blockIdx.x*blockDim.x + threadIdx.x;
    if (idx >= N_NODES*128) return;
    int n = idx >> 7, j = idx & 127;
    float a = 0.f;
    if (j < 32) a = bf[j];
    else if (j >= 64 && j < 96) a = bs[j-64];
    const float4* xr = (const float4*)(x + n*32);
    #pragma unroll
    for (int k4 = 0; k4 < 8; k4++){
        float4 v = xr[k4];
        int k = k4*4;
        a = fmaf(v.x, sC[(k  )*128 + j], a);
        a = fmaf(v.y, sC[(k+1)*128 + j], a);
        a = fmaf(v.z, sC[(k+2)*128 + j], a);
        a = fmaf(v.w, sC[(k+3)*128 + j], a);
    }
    AB[idx] = a;
}

// CGConv edge kernel using precomputed AB. Per edge-lane: 4 gathers + ea part
// (8x32 weights in 16 VGPRs) + activation + one atomicAdd. No LDS.
__global__ __launch_bounds__(256) void k_cgedge(
    const float* __restrict__ AB, const float* __restrict__ ea,
    const int* __restrict__ srcv, const int* __restrict__ dstv,
    const float* __restrict__ Wf, const float* __restrict__ Ws,
    float* __restrict__ acc)
{
    const int lane = threadIdx.x & 31;
    const int g = threadIdx.x >> 5;    // edge slot 0..7 within block
    float wf[8], ws[8];
    #pragma unroll
    for (int k = 0; k < 8; k++){
        wf[k] = Wf[(64+k)*32 + lane];  // ea-part weights
        ws[k] = Ws[(64+k)*32 + lane];
    }
    for (int e = blockIdx.x*8 + g; e < N_EDGES; e += gridDim.x*8){
        int s = srcv[e], d = dstv[e];
        const float* Ad = AB + (size_t)d*128;
        const float* As = AB + (size_t)s*128;
        float af = Ad[lane]      + As[32 + lane];
        float av = Ad[64 + lane] + As[96 + lane];
        const float4* ep = (const float4*)(ea + (size_t)e*8);
        float4 e0 = ep[0], e1 = ep[1];
        af = fmaf(e0.x, wf[0], af); av = fmaf(e0.x, ws[0], av);
        af = fmaf(e0.y, wf[1], af); av = fmaf(e0.y, ws[1], av);
        af = fmaf(e0.z, wf[2], af); av = fmaf(e0.z, ws[2], av);
        af = fmaf(e0.w, wf[3], af); av = fmaf(e0.w, ws[3], av);
        af = fmaf(e1.x, wf[4], af); av = fmaf(e1.x, ws[4], av);
        af = fmaf(e1.y, wf[5], af); av = fmaf(e1.y, ws[5], av);
        af = fmaf(e1.z, wf[6], af); av = fmaf(e1.z, ws[6], av);
        af = fmaf(e1.w, wf[7], af); av = fmaf(e1.w, ws[7], av);
        atomicAdd(&acc[(size_t)d*32 + lane], sigmoidf_(af)*softplusf_(av));
    }
}

// out[N][Co] = in[N][Ci] @ W[Ci][Co]   (no bias)
template<int Ci, int Co>
__global__ void k_linear(const float* __restrict__ in, const float* __restrict__ W,
                         float* __restrict__ out, int N){
    __shared__ float sW[Ci*Co];
    for (int i = threadIdx.x; i < Ci*Co; i += blockDim.x) sW[i] = W[i];
    __syncthreads();
    int idx = blockIdx.x*blockDim.x + threadIdx.x;
    if (idx >= N*Co) return;
    int n = idx / Co, co = idx % Co;
    const float* row = in + n*Ci;
    float a = 0.f;
    #pragma unroll
    for (int k = 0; k < Ci; k++) a = fmaf(row[k], sW[k*Co + co], a);
    out[idx] = a;
}

// attention logits per node: al[n][h] = sum_c hg[n][h][c] * a[h][c]
template<int C>
__global__ void k_al(const float* __restrict__ hg, const float* __restrict__ a_src,
                     const float* __restrict__ a_dst,
                     float* __restrict__ als, float* __restrict__ ald){
    int idx = blockIdx.x*blockDim.x + threadIdx.x;
    if (idx >= N_NODES*HEADS) return;
    int n = idx/HEADS, h = idx%HEADS;
    const float* row = hg + (n*HEADS + h)*C;
    float as = 0.f, ad = 0.f;
    #pragma unroll
    for (int c = 0; c < C; c++){
        float v = row[c];
        as = fmaf(v, a_src[h*C + c], as);
        ad = fmaf(v, a_dst[h*C + c], ad);
    }
    als[idx] = as; ald[idx] = ad;
}

static __device__ __forceinline__ void edge_sd(int e, const int* srcv, const int* dstv, int& s, int& d){
    if (e < N_EDGES){ s = srcv[e]; d = dstv[e]; }
    else            { s = e - N_EDGES; d = s; }   // self loops appended
}

__global__ void k_gat_max(const int* __restrict__ srcv, const int* __restrict__ dstv,
                          const float* __restrict__ als, const float* __restrict__ ald,
                          float* __restrict__ m){
    int idx = blockIdx.x*blockDim.x + threadIdx.x;
    if (idx >= E_SL*HEADS) return;
    int e = idx/HEADS, h = idx%HEADS;
    int s, d; edge_sd(e, srcv, dstv, s, d);
    float v = lrelu02(als[s*HEADS + h] + ald[d*HEADS + h]);
    atomicMaxF(&m[d*HEADS + h], v);
}

__global__ void k_gat_sum(const int* __restrict__ srcv, const int* __restrict__ dstv,
                          const float* __restrict__ als, const float* __restrict__ ald,
                          const float* __restrict__ m, float* __restrict__ P,
                          float* __restrict__ S){
    int idx = blockIdx.x*blockDim.x + threadIdx.x;
    if (idx >= E_SL*HEADS) return;
    int e = idx/HEADS, h = idx%HEADS;
    int s, d; edge_sd(e, srcv, dstv, s, d);
    float v = lrelu02(als[s*HEADS + h] + ald[d*HEADS + h]);
    float p = __expf(v - m[d*HEADS + h]);
    P[idx] = p;
    atomicAdd(&S[d*HEADS + h], p);
}

__global__ void k_gat_alpha(const int* __restrict__ dstv, const float* __restrict__ S,
                            float* __restrict__ P){
    int idx = blockIdx.x*blockDim.x + threadIdx.x;
    if (idx >= E_SL*HEADS) return;
    int e = idx/HEADS, h = idx%HEADS;
    int d = (e < N_EDGES) ? dstv[e] : (e - N_EDGES);
    P[idx] = P[idx] / (S[d*HEADS + h] + 1e-16f);
}

// O[dst][h][c] += hg[src][h][c] * alpha[e][h]
template<int C>
__global__ void k_gat_agg(const int* __restrict__ srcv, const int* __restrict__ dstv,
                          const float* __restrict__ hg, const float* __restrict__ P,
                          float* __restrict__ O){
    const int HC = HEADS*C;
    int idx = blockIdx.x*blockDim.x + threadIdx.x;
    if (idx >= E_SL*HC) return;
    int e = idx / HC, hc = idx % HC;
    int h = hc / C;
    int s, d; edge_sd(e, srcv, dstv, s, d);
    float alpha = P[e*HEADS + h];
    atomicAdd(&O[d*HC + hc], hg[s*HC + hc] * alpha);
}

template<int HC>
__global__ void k_bias_relu(float* __restrict__ O, const float* __restrict__ b){
    int idx = blockIdx.x*blockDim.x + threadIdx.x;
    if (idx >= N_NODES*HC) return;
    O[idx] = fmaxf(O[idx] + b[idx % HC], 0.f);
}

// One block per graph; batch sorted -> contiguous node range via binary search.
__global__ __launch_bounds__(256) void k_pool2(
    const float* __restrict__ O2, const int* __restrict__ batch,
    float* __restrict__ gmean){
    __shared__ int s_range[2];
    __shared__ float red[240];
    const int gr = blockIdx.x;
    if (threadIdx.x < 2){
        int key = gr + threadIdx.x;           // lower_bound(batch, key)
        int lo = 0, hi = N_NODES;
        while (lo < hi){ int mid = (lo+hi) >> 1; if (batch[mid] < key) lo = mid+1; else hi = mid; }
        s_range[threadIdx.x] = lo;
    }
    __syncthreads();
    const int lo = s_range[0], hi = s_range[1];
    if (threadIdx.x < 240){
        const int c = threadIdx.x % 48, r = threadIdx.x / 48;
        float a = 0.f;
        for (int n = lo + r; n < hi; n += 5) a += O2[n*48 + c];
        red[threadIdx.x] = a;
    }
    __syncthreads();
    if (threadIdx.x < 48){
        float a = red[threadIdx.x] + red[48+threadIdx.x] + red[96+threadIdx.x]
                + red[144+threadIdx.x] + red[192+threadIdx.x];
        float cnt = (float)(hi - lo);
        gmean[gr*48 + threadIdx.x] = a / fmaxf(cnt, 1.f);
    }
}

__global__ __launch_bounds__(1024) void k_mlp(
    const float* __restrict__ g /* [64][48] graph means */,
    const float* __restrict__ Wl1, const float* __restrict__ bl1,
    const float* __restrict__ Wl2, const float* __restrict__ bl2,
    float* __restrict__ out){
    __shared__ float gs[N_GRAPHS*48];
    __shared__ float g1[N_GRAPHS*16];
    int t = threadIdx.x;
    for (int i = t; i < N_GRAPHS*48; i += 1024) gs[i] = g[i];
    __syncthreads();
    if (t < N_GRAPHS*16){
        int n = t/16, j = t%16;
        float a = bl1[j];
        #pragma unroll
        for (int k = 0; k < 48; k++) a = fmaf(gs[n*48 + k], Wl1[k*16 + j], a);
        g1[t] = fmaxf(a, 0.f);
    }
    __syncthreads();
    if (t < N_GRAPHS*10){
        int n = t/10, j = t%10;
        float a = bl2[j];
        #pragma unroll
        for (int k = 0; k < 16; k++) a = fmaf(g1[n*16 + k], Wl2[k*10 + j], a);
        out[n*10 + j] = a;
    }
}

extern "C" void kernel_launch(void* const* d_in, const int* in_sizes, int n_in,
                              void* d_out, int out_size, void* d_ws, size_t ws_size,
                              hipStream_t stream) {
    const float* x    = (const float*)d_in[0];
    const float* ea   = (const float*)d_in[1];
    const int*   ei   = (const int*)  d_in[2];
    const int*   batch= (const int*)  d_in[3];
    const float* Wf1 = (const float*)d_in[4];  const float* bf1 = (const float*)d_in[5];
    const float* Ws1 = (const float*)d_in[6];  const float* bs1 = (const float*)d_in[7];
    const float* Wf2 = (const float*)d_in[8];  const float* bf2 = (const float*)d_in[9];
    const float* Ws2 = (const float*)d_in[10]; const float* bs2 = (const float*)d_in[11];
    const float* Wg1 = (const float*)d_in[12];
    const float* asrc1=(const float*)d_in[13]; const float* adst1=(const float*)d_in[14];
    const float* bg1 = (const float*)d_in[15];
    const float* Wg2 = (const float*)d_in[16];
    const float* asrc2=(const float*)d_in[17]; const float* adst2=(const float*)d_in[18];
    const float* bg2 = (const float*)d_in[19];
    const float* Wl1 = (const float*)d_in[20]; const float* bl1 = (const float*)d_in[21];
    const float* Wl2 = (const float*)d_in[22]; const float* bl2 = (const float*)d_in[23];
    float* out = (float*)d_out;

    const int* srcv = ei;
    const int* dstv = ei + N_EDGES;

    // ---- workspace arena (floats); ~70.3 MB, overlays by lifetime ----
    float* w   = (float*)d_ws;
    float* X0  = w;                 // 1.6M  conv1 acc; later GAT1 input
    float* X1  = X0 + 1600000;      // 1.6M  relu(conv1) = conv2 input
    float* X2  = X1 + 1600000;      // 1.6M  conv2 acc
    float* HG1 = X2 + 1600000;      // 4.8M  (GAT1 h)
    float* O1  = HG1 + 4800000;     // 4.8M
    float* P   = O1 + 4800000;      // 2.55M
    float* ALs = P + 2550000;       // 150k
    float* ALd = ALs + 150000;      // 150k
    float* M   = ALd + 150000;      // 150k
    float* S   = M + 150000;        // 150k
    float* GM  = S + 150000;        // 64*48
    // overlays:
    float* AB  = HG1;               // 6.4M  (conv phase only; dead before HG1/O1 written)
    float* HG2 = HG1;               // GAT2 h (2.4M)
    float* O2  = HG1 + 2400000;     // 2.4M
    (void)ws_size; (void)in_sizes; (void)n_in; (void)out_size;

    auto G = [](int n){ return (n + 255)/256; };

    // ---- CGConv 1 ----
    k_pre<<<G(N_NODES*128), 256, 0, stream>>>(x, Wf1, bf1, Ws1, bs1, AB);
    hipMemcpyAsync(X0, x, (size_t)1600000*sizeof(float), hipMemcpyDeviceToDevice, stream);
    k_cgedge<<<1280, 256, 0, stream>>>(AB, ea, srcv, dstv, Wf1, Ws1, X0);
    k_relu2<<<G(1600000), 256, 0, stream>>>(X0, X1, X2, 1600000);   // X1 = input, X2 = acc init

    // ---- CGConv 2 ----
    k_pre<<<G(N_NODES*128), 256, 0, stream>>>(X1, Wf2, bf2, Ws2, bs2, AB);
    k_cgedge<<<1280, 256, 0, stream>>>(AB, ea, srcv, dstv, Wf2, Ws2, X2);
    k_relu2<<<G(1600000), 256, 0, stream>>>(X2, X0, nullptr, 1600000); // X0 = GAT1 input

    // ---- GATConv 1 (C=32, HC=96) ----
    k_linear<32,96><<<G(N_NODES*96), 256, 0, stream>>>(X0, Wg1, HG1, N_NODES);
    k_al<32><<<G(N_NODES*HEADS), 256, 0, stream>>>(HG1, asrc1, adst1, ALs, ALd);
    k_fill<<<G(150000), 256, 0, stream>>>(M, -INFINITY, 150000);
    k_fill<<<G(150000), 256, 0, stream>>>(S, 0.f, 150000);
    k_fill<<<G(4800000), 256, 0, stream>>>(O1, 0.f, 4800000);
    k_gat_max<<<G(E_SL*HEADS), 256, 0, stream>>>(srcv, dstv, ALs, ALd, M);
    k_gat_sum<<<G(E_SL*HEADS), 256, 0, stream>>>(srcv, dstv, ALs, ALd, M, P, S);
    k_gat_alpha<<<G(E_SL*HEADS), 256, 0, stream>>>(dstv, S, P);
    k_gat_agg<32><<<G(E_SL*96), 256, 0, stream>>>(srcv, dstv, HG1, P, O1);
    k_bias_relu<96><<<G(N_NODES*96), 256, 0, stream>>>(O1, bg1);

    // ---- GATConv 2 (C=16, HC=48) ----
    k_linear<96,48><<<G(N_NODES*48), 256, 0, stream>>>(O1, Wg2, HG2, N_NODES);
    k_al<16><<<G(N_NODES*HEADS), 256, 0, stream>>>(HG2, asrc2, adst2, ALs, ALd);
    k_fill<<<G(150000), 256, 0, stream>>>(M, -INFINITY, 150000);
    k_fill<<<G(150000), 256, 0, stream>>>(S, 0.f, 150000);
    k_fill<<<G(2400000), 256, 0, stream>>>(O2, 0.f, 2400000);
    k_gat_max<<<G(E_SL*HEADS), 256, 0, stream>>>(srcv, dstv, ALs, ALd, M);
    k_gat_sum<<<G(E_SL*HEADS), 256, 0, stream>>>(srcv, dstv, ALs, ALd, M, P, S);
    k_gat_alpha<<<G(E_SL*HEADS), 256, 0, stream>>>(dstv, S, P);
    k_gat_agg<16><<<G(E_SL*48), 256, 0, stream>>>(srcv, dstv, HG2, P, O2);
    k_bias_relu<48><<<G(N_NODES*48), 256, 0, stream>>>(O2, bg2);

    // ---- pool + MLP ----
    k_pool2<<<N_GRAPHS, 256, 0, stream>>>(O2, batch, GM);
    k_mlp<<<1, 1024, 0, stream>>>(GM, Wl1, bl1, Wl2, bl2, out);
}

// Round 4
// 1125.489 us; speedup vs baseline: 1.6809x; 1.1277x over previous
//
#include <hip/hip_runtime.h>
#include <math.h>

#define N_NODES 50000
#define N_EDGES 800000
#define IN_FEAT 32
#define EDGE_FEAT 8
#define Z_DIM 72
#define HEADS 3
#define N_GRAPHS 64

static __device__ __forceinline__ float sigmoidf_(float x){ return 1.f/(1.f+__expf(-x)); }
static __device__ __forceinline__ float softplusf_(float x){ return fmaxf(x,0.f) + log1pf(__expf(-fabsf(x))); }
static __device__ __forceinline__ float lrelu02(float x){ return x > 0.f ? x : 0.2f*x; }

// ---------------- CSR build (per call; ws is re-poisoned) ----------------
__global__ void k_zero_i(int* __restrict__ p, int n){
    int i = blockIdx.x*blockDim.x + threadIdx.x;
    if (i < n) p[i] = 0;
}
__global__ void k_hist(const int* __restrict__ dstv, int* __restrict__ deg){
    int e = blockIdx.x*blockDim.x + threadIdx.x;
    if (e < N_EDGES) atomicAdd(&deg[dstv[e]], 1);
}
// single-block exclusive scan over deg -> rowptr[0..N], also copies into cur
__global__ __launch_bounds__(1024) void k_scan(const int* __restrict__ deg,
                                               int* __restrict__ rowptr,
                                               int* __restrict__ cur){
    __shared__ int sdata[1024];
    __shared__ int s_off;
    if (threadIdx.x == 0) s_off = 0;
    __syncthreads();
    for (int base = 0; base < N_NODES; base += 1024){
        int i = base + threadIdx.x;
        int v = (i < N_NODES) ? deg[i] : 0;
        sdata[threadIdx.x] = v;
        __syncthreads();
        for (int st = 1; st < 1024; st <<= 1){
            int t = (threadIdx.x >= st) ? sdata[threadIdx.x - st] : 0;
            __syncthreads();
            sdata[threadIdx.x] += t;
            __syncthreads();
        }
        int excl = s_off + sdata[threadIdx.x] - v;
        if (i < N_NODES){ rowptr[i] = excl; cur[i] = excl; }
        __syncthreads();
        if (threadIdx.x == 0) s_off += sdata[1023];
        __syncthreads();
    }
    if (threadIdx.x == 0) rowptr[N_NODES] = s_off;
}
__global__ void k_scatter(const int* __restrict__ srcv, const int* __restrict__ dstv,
                          int* __restrict__ cur, int* __restrict__ eord,
                          int* __restrict__ esrc){
    int e = blockIdx.x*blockDim.x + threadIdx.x;
    if (e >= N_EDGES) return;
    int d = dstv[e];
    int pos = atomicAdd(&cur[d], 1);
    eord[pos] = e;
    esrc[pos] = srcv[e];
}

// ---------------- CGConv ----------------
// AB[n][128] = [ x@Wf_dst + bf | x@Wf_src | x@Ws_dst + bs | x@Ws_src ]
__global__ __launch_bounds__(256) void k_pre(
    const float* __restrict__ x,
    const float* __restrict__ Wf, const float* __restrict__ bf,
    const float* __restrict__ Ws, const float* __restrict__ bs,
    float* __restrict__ AB)
{
    __shared__ float sC[32*128];
    for (int i = threadIdx.x; i < 32*128; i += 256){
        int k = i >> 7, j = i & 127;
        float w;
        if      (j < 32)  w = Wf[k*32 + j];
        else if (j < 64)  w = Wf[(32+k)*32 + (j-32)];
        else if (j < 96)  w = Ws[k*32 + (j-64)];
        else              w = Ws[(32+k)*32 + (j-96)];
        sC[i] = w;
    }
    __syncthreads();
    int idx = blockIdx.x*blockDim.x + threadIdx.x;
    if (idx >= N_NODES*128) return;
    int n = idx >> 7, j = idx & 127;
    float a = 0.f;
    if (j < 32) a = bf[j];
    else if (j >= 64 && j < 96) a = bs[j-64];
    const float4* xr = (const float4*)(x + n*32);
    #pragma unroll
    for (int k4 = 0; k4 < 8; k4++){
        float4 v = xr[k4];
        int k = k4*4;
        a = fmaf(v.x, sC[(k  )*128 + j], a);
        a = fmaf(v.y, sC[(k+1)*128 + j], a);
        a = fmaf(v.z, sC[(k+2)*128 + j], a);
        a = fmaf(v.w, sC[(k+3)*128 + j], a);
    }
    AB[idx] = a;
}

// Gather form: one wave (64) per node. Lanes 0-31 build the lin_f pre-act,
// lanes 32-63 the lin_s pre-act; __shfl_xor(32) pairs them; lanes 0-31
// accumulate msg and write out = relu(x + sum). No atomics, no LDS.
__global__ __launch_bounds__(256) void k_cg_gather(
    const float* __restrict__ xin, const float* __restrict__ AB,
    const float* __restrict__ ea,
    const int* __restrict__ rowptr, const int* __restrict__ eord,
    const int* __restrict__ esrc,
    const float* __restrict__ Wf, const float* __restrict__ Ws,
    float* __restrict__ outp)
{
    const int lane = threadIdx.x & 63;
    const int half = lane >> 5, c = lane & 31;
    const float* Wz = half ? Ws : Wf;
    float w0 = Wz[(64+0)*32+c], w1 = Wz[(64+1)*32+c], w2 = Wz[(64+2)*32+c], w3 = Wz[(64+3)*32+c];
    float w4 = Wz[(64+4)*32+c], w5 = Wz[(64+5)*32+c], w6 = Wz[(64+6)*32+c], w7 = Wz[(64+7)*32+c];
    const int d = (blockIdx.x*blockDim.x + threadIdx.x) >> 6;
    if (d >= N_NODES) return;
    const int lo = rowptr[d], hi = rowptr[d+1];
    const float base = AB[(size_t)d*128 + half*64 + c];   // AF_d[c] or AS_d[c]
    float acc = 0.f;
    for (int i = lo; i < hi; i++){
        int e = eord[i], s = esrc[i];
        float v = base + AB[(size_t)s*128 + half*64 + 32 + c];  // + BF_s / BS_s
        const float4* ep = (const float4*)(ea + (size_t)e*8);
        float4 e0 = ep[0], e1 = ep[1];
        v = fmaf(e0.x, w0, v); v = fmaf(e0.y, w1, v);
        v = fmaf(e0.z, w2, v); v = fmaf(e0.w, w3, v);
        v = fmaf(e1.x, w4, v); v = fmaf(e1.y, w5, v);
        v = fmaf(e1.z, w6, v); v = fmaf(e1.w, w7, v);
        float other = __shfl_xor(v, 32, 64);
        if (half == 0) acc += sigmoidf_(v) * softplusf_(other);
    }
    if (half == 0) outp[(size_t)d*32 + c] = fmaxf(xin[(size_t)d*32 + c] + acc, 0.f);
}

// ---------------- GAT ----------------
template<int Ci, int Co>
__global__ void k_linear(const float* __restrict__ in, const float* __restrict__ W,
                         float* __restrict__ out, int N){
    __shared__ float sW[Ci*Co];
    for (int i = threadIdx.x; i < Ci*Co; i += blockDim.x) sW[i] = W[i];
    __syncthreads();
    int idx = blockIdx.x*blockDim.x + threadIdx.x;
    if (idx >= N*Co) return;
    int n = idx / Co, co = idx % Co;
    const float* row = in + (size_t)n*Ci;
    float a = 0.f;
    #pragma unroll
    for (int k = 0; k < Ci; k++) a = fmaf(row[k], sW[k*Co + co], a);
    out[idx] = a;
}

template<int C>
__global__ void k_al(const float* __restrict__ hg, const float* __restrict__ a_src,
                     const float* __restrict__ a_dst,
                     float* __restrict__ als, float* __restrict__ ald){
    int idx = blockIdx.x*blockDim.x + threadIdx.x;
    if (idx >= N_NODES*HEADS) return;
    int n = idx/HEADS, h = idx%HEADS;
    const float* row = hg + ((size_t)n*HEADS + h)*C;
    float as = 0.f, ad = 0.f;
    #pragma unroll
    for (int c = 0; c < C; c++){
        float v = row[c];
        as = fmaf(v, a_src[h*C + c], as);
        ad = fmaf(v, a_dst[h*C + c], ad);
    }
    als[idx] = as; ald[idx] = ad;
}

// Fused GAT per node: softmax (2-pass over CSR edges + self loop) + weighted
// aggregation + bias + relu. One block per node; thread=(head,channel); the
// per-head max/sum are computed redundantly per channel (loads broadcast) so
// no cross-thread communication is needed at all.
template<int C>
__global__ void k_gat_fused(
    const float* __restrict__ hg, const int* __restrict__ rowptr,
    const int* __restrict__ esrc,
    const float* __restrict__ als, const float* __restrict__ ald,
    const float* __restrict__ bias, float* __restrict__ O)
{
    const int d = blockIdx.x;
    const int tid = threadIdx.x;
    if (tid >= HEADS*C) return;
    const int h = tid / C, c = tid % C;
    const int lo = rowptr[d], hi = rowptr[d+1];
    const float ald_d = ald[d*HEADS + h];
    const float self_logit = lrelu02(als[d*HEADS + h] + ald_d);
    float m = self_logit;
    for (int i = lo; i < hi; i++)
        m = fmaxf(m, lrelu02(als[esrc[i]*HEADS + h] + ald_d));
    float psum = __expf(self_logit - m);
    float acc  = psum * hg[((size_t)d*HEADS + h)*C + c];
    for (int i = lo; i < hi; i++){
        int s = esrc[i];
        float p = __expf(lrelu02(als[s*HEADS + h] + ald_d) - m);
        psum += p;
        acc = fmaf(p, hg[((size_t)s*HEADS + h)*C + c], acc);
    }
    O[((size_t)d*HEADS + h)*C + c] = fmaxf(acc/(psum + 1e-16f) + bias[h*C + c], 0.f);
}

// ---------------- pool + MLP ----------------
__global__ __launch_bounds__(256) void k_pool2(
    const float* __restrict__ O2, const int* __restrict__ batch,
    float* __restrict__ gmean){
    __shared__ int s_range[2];
    __shared__ float red[240];
    const int gr = blockIdx.x;
    if (threadIdx.x < 2){
        int key = gr + threadIdx.x;
        int lo = 0, hi = N_NODES;
        while (lo < hi){ int mid = (lo+hi) >> 1; if (batch[mid] < key) lo = mid+1; else hi = mid; }
        s_range[threadIdx.x] = lo;
    }
    __syncthreads();
    const int lo = s_range[0], hi = s_range[1];
    if (threadIdx.x < 240){
        const int c = threadIdx.x % 48, r = threadIdx.x / 48;
        float a = 0.f;
        for (int n = lo + r; n < hi; n += 5) a += O2[(size_t)n*48 + c];
        red[threadIdx.x] = a;
    }
    __syncthreads();
    if (threadIdx.x < 48){
        float a = red[threadIdx.x] + red[48+threadIdx.x] + red[96+threadIdx.x]
                + red[144+threadIdx.x] + red[192+threadIdx.x];
        float cnt = (float)(hi - lo);
        gmean[gr*48 + threadIdx.x] = a / fmaxf(cnt, 1.f);
    }
}

__global__ __launch_bounds__(1024) void k_mlp(
    const float* __restrict__ g,
    const float* __restrict__ Wl1, const float* __restrict__ bl1,
    const float* __restrict__ Wl2, const float* __restrict__ bl2,
    float* __restrict__ out){
    __shared__ float gs[N_GRAPHS*48];
    __shared__ float g1[N_GRAPHS*16];
    int t = threadIdx.x;
    for (int i = t; i < N_GRAPHS*48; i += 1024) gs[i] = g[i];
    __syncthreads();
    if (t < N_GRAPHS*16){
        int n = t/16, j = t%16;
        float a = bl1[j];
        #pragma unroll
        for (int k = 0; k < 48; k++) a = fmaf(gs[n*48 + k], Wl1[k*16 + j], a);
        g1[t] = fmaxf(a, 0.f);
    }
    __syncthreads();
    if (t < N_GRAPHS*10){
        int n = t/10, j = t%10;
        float a = bl2[j];
        #pragma unroll
        for (int k = 0; k < 16; k++) a = fmaf(g1[n*16 + k], Wl2[k*10 + j], a);
        out[n*10 + j] = a;
    }
}

extern "C" void kernel_launch(void* const* d_in, const int* in_sizes, int n_in,
                              void* d_out, int out_size, void* d_ws, size_t ws_size,
                              hipStream_t stream) {
    const float* x    = (const float*)d_in[0];
    const float* ea   = (const float*)d_in[1];
    const int*   ei   = (const int*)  d_in[2];
    const int*   batch= (const int*)  d_in[3];
    const float* Wf1 = (const float*)d_in[4];  const float* bf1 = (const float*)d_in[5];
    const float* Ws1 = (const float*)d_in[6];  const float* bs1 = (const float*)d_in[7];
    const float* Wf2 = (const float*)d_in[8];  const float* bf2 = (const float*)d_in[9];
    const float* Ws2 = (const float*)d_in[10]; const float* bs2 = (const float*)d_in[11];
    const float* Wg1 = (const float*)d_in[12];
    const float* asrc1=(const float*)d_in[13]; const float* adst1=(const float*)d_in[14];
    const float* bg1 = (const float*)d_in[15];
    const float* Wg2 = (const float*)d_in[16];
    const float* asrc2=(const float*)d_in[17]; const float* adst2=(const float*)d_in[18];
    const float* bg2 = (const float*)d_in[19];
    const float* Wl1 = (const float*)d_in[20]; const float* bl1 = (const float*)d_in[21];
    const float* Wl2 = (const float*)d_in[22]; const float* bl2 = (const float*)d_in[23];
    float* out = (float*)d_out;

    const int* srcv = ei;
    const int* dstv = ei + N_EDGES;

    // ---- workspace arena, ~66 MB with lifetime overlays ----
    float* w   = (float*)d_ws;
    float* XA  = w;                  // 1.6M  relu(conv1)
    float* XB  = XA + 1600000;       // 1.6M  relu(conv2) = GAT1 input
    float* R2  = XB + 1600000;       // 6.4M  AB (conv) -> HG1 (4.8M) -> HG2|O2 (2.4M+2.4M)
    float* R3  = R2 + 6400000;       // 4.8M  O1 (GAT1 out)
    float* ALs = R3 + 4800000;       // 150k
    float* ALd = ALs + 150000;       // 150k
    float* GM  = ALd + 150000;       // 3072
    int* deg    = (int*)(GM + 3072); // 50k
    int* cur    = deg + 50000;       // 50k
    int* rowptr = cur + 50000;       // 50001
    int* eord   = rowptr + 50001;    // 800k
    int* esrc   = eord + 800000;     // 800k
    float* AB  = R2;
    float* HG1 = R2;
    float* HG2 = R2;
    float* O2  = R2 + 2400000;
    float* O1  = R3;
    (void)ws_size; (void)in_sizes; (void)n_in; (void)out_size;

    auto G = [](int n){ return (n + 255)/256; };

    // ---- CSR by dst (built once, used by both convs and both GATs) ----
    k_zero_i<<<G(N_NODES), 256, 0, stream>>>(deg, N_NODES);
    k_hist<<<G(N_EDGES), 256, 0, stream>>>(dstv, deg);
    k_scan<<<1, 1024, 0, stream>>>(deg, rowptr, cur);
    k_scatter<<<G(N_EDGES), 256, 0, stream>>>(srcv, dstv, cur, eord, esrc);

    // ---- CGConv 1 ----
    k_pre<<<G(N_NODES*128), 256, 0, stream>>>(x, Wf1, bf1, Ws1, bs1, AB);
    k_cg_gather<<<(N_NODES*64)/256, 256, 0, stream>>>(x, AB, ea, rowptr, eord, esrc, Wf1, Ws1, XA);

    // ---- CGConv 2 ----
    k_pre<<<G(N_NODES*128), 256, 0, stream>>>(XA, Wf2, bf2, Ws2, bs2, AB);
    k_cg_gather<<<(N_NODES*64)/256, 256, 0, stream>>>(XA, AB, ea, rowptr, eord, esrc, Wf2, Ws2, XB);

    // ---- GATConv 1 (C=32) ----
    k_linear<32,96><<<G(N_NODES*96), 256, 0, stream>>>(XB, Wg1, HG1, N_NODES);
    k_al<32><<<G(N_NODES*HEADS), 256, 0, stream>>>(HG1, asrc1, adst1, ALs, ALd);
    k_gat_fused<32><<<N_NODES, 128, 0, stream>>>(HG1, rowptr, esrc, ALs, ALd, bg1, O1);

    // ---- GATConv 2 (C=16) ----
    k_linear<96,48><<<G(N_NODES*48), 256, 0, stream>>>(O1, Wg2, HG2, N_NODES);
    k_al<16><<<G(N_NODES*HEADS), 256, 0, stream>>>(HG2, asrc2, adst2, ALs, ALd);
    k_gat_fused<16><<<N_NODES, 64, 0, stream>>>(HG2, rowptr, esrc, ALs, ALd, bg2, O2);

    // ---- pool + MLP ----
    k_pool2<<<N_GRAPHS, 256, 0, stream>>>(O2, batch, GM);
    k_mlp<<<1, 1024, 0, stream>>>(GM, Wl1, bl1, Wl2, bl2, out);
}

// Round 5
// 955.495 us; speedup vs baseline: 1.9799x; 1.1779x over previous
//
#include <hip/hip_runtime.h>
#include <math.h>

#define N_NODES 50000
#define N_EDGES 800000
#define IN_FEAT 32
#define EDGE_FEAT 8
#define Z_DIM 72
#define HEADS 3
#define N_GRAPHS 64

// fast activations: hardware exp/log/rcp. absmax budget is 4.2e-2; these are ~1e-6.
static __device__ __forceinline__ float fast_sigmoid(float x){
    return __builtin_amdgcn_rcpf(1.f + __expf(-x));   // exp(-x)->inf => rcp->0, correct tail
}
static __device__ __forceinline__ float fast_softplus(float x){
    return fmaxf(x, 0.f) + __logf(1.f + __expf(-fabsf(x)));
}
static __device__ __forceinline__ float lrelu02(float x){ return x > 0.f ? x : 0.2f*x; }

// ---------------- CSR build (per call; ws is re-poisoned) ----------------
__global__ void k_zero_i(int* __restrict__ p, int n){
    int i = blockIdx.x*blockDim.x + threadIdx.x;
    if (i < n) p[i] = 0;
}
__global__ void k_hist(const int* __restrict__ dstv, int* __restrict__ deg){
    int e = blockIdx.x*blockDim.x + threadIdx.x;
    if (e < N_EDGES) atomicAdd(&deg[dstv[e]], 1);
}
// single-block exclusive scan over deg -> rowptr[0..N], also copies into cur
__global__ __launch_bounds__(1024) void k_scan(const int* __restrict__ deg,
                                               int* __restrict__ rowptr,
                                               int* __restrict__ cur){
    __shared__ int sdata[1024];
    __shared__ int s_off;
    if (threadIdx.x == 0) s_off = 0;
    __syncthreads();
    for (int base = 0; base < N_NODES; base += 1024){
        int i = base + threadIdx.x;
        int v = (i < N_NODES) ? deg[i] : 0;
        sdata[threadIdx.x] = v;
        __syncthreads();
        for (int st = 1; st < 1024; st <<= 1){
            int t = (threadIdx.x >= st) ? sdata[threadIdx.x - st] : 0;
            __syncthreads();
            sdata[threadIdx.x] += t;
            __syncthreads();
        }
        int excl = s_off + sdata[threadIdx.x] - v;
        if (i < N_NODES){ rowptr[i] = excl; cur[i] = excl; }
        __syncthreads();
        if (threadIdx.x == 0) s_off += sdata[1023];
        __syncthreads();
    }
    if (threadIdx.x == 0) rowptr[N_NODES] = s_off;
}
// scatter: CSR edge srcs + permute edge_attr into CSR order (coalesced reads later)
__global__ void k_scatter(const int* __restrict__ srcv, const int* __restrict__ dstv,
                          const float* __restrict__ ea,
                          int* __restrict__ cur, int* __restrict__ esrc,
                          float* __restrict__ eacsr){
    int e = blockIdx.x*blockDim.x + threadIdx.x;
    if (e >= N_EDGES) return;
    int d = dstv[e];
    int pos = atomicAdd(&cur[d], 1);
    esrc[pos] = srcv[e];
    const float4* s4 = (const float4*)(ea + (size_t)e*8);
    float4 a0 = s4[0], a1 = s4[1];
    float4* d4 = (float4*)(eacsr + (size_t)pos*8);
    d4[0] = a0; d4[1] = a1;
}

// ---------------- CGConv ----------------
// AB[n][128] = [ x@Wf_dst + bf | x@Wf_src | x@Ws_dst + bs | x@Ws_src ]
__global__ __launch_bounds__(256) void k_pre(
    const float* __restrict__ x,
    const float* __restrict__ Wf, const float* __restrict__ bf,
    const float* __restrict__ Ws, const float* __restrict__ bs,
    float* __restrict__ AB)
{
    __shared__ float sC[32*128];
    for (int i = threadIdx.x; i < 32*128; i += 256){
        int k = i >> 7, j = i & 127;
        float w;
        if      (j < 32)  w = Wf[k*32 + j];
        else if (j < 64)  w = Wf[(32+k)*32 + (j-32)];
        else if (j < 96)  w = Ws[k*32 + (j-64)];
        else              w = Ws[(32+k)*32 + (j-96)];
        sC[i] = w;
    }
    __syncthreads();
    int idx = blockIdx.x*blockDim.x + threadIdx.x;
    if (idx >= N_NODES*128) return;
    int n = idx >> 7, j = idx & 127;
    float a = 0.f;
    if (j < 32) a = bf[j];
    else if (j >= 64 && j < 96) a = bs[j-64];
    const float4* xr = (const float4*)(x + (size_t)n*32);
    #pragma unroll
    for (int k4 = 0; k4 < 8; k4++){
        float4 v = xr[k4];
        int k = k4*4;
        a = fmaf(v.x, sC[(k  )*128 + j], a);
        a = fmaf(v.y, sC[(k+1)*128 + j], a);
        a = fmaf(v.z, sC[(k+2)*128 + j], a);
        a = fmaf(v.w, sC[(k+3)*128 + j], a);
    }
    AB[idx] = a;
}

// Gather form: one wave (64) per node; lanes 0-31 lin_f, 32-63 lin_s;
// __shfl_xor(32) pairs pre-acts; fast activations; no atomics, no LDS.
__global__ __launch_bounds__(256) void k_cg_gather(
    const float* __restrict__ xin, const float* __restrict__ AB,
    const float* __restrict__ eacsr,
    const int* __restrict__ rowptr, const int* __restrict__ esrc,
    const float* __restrict__ Wf, const float* __restrict__ Ws,
    float* __restrict__ outp)
{
    const int lane = threadIdx.x & 63;
    const int half = lane >> 5, c = lane & 31;
    const float* Wz = half ? Ws : Wf;
    float w0 = Wz[(64+0)*32+c], w1 = Wz[(64+1)*32+c], w2 = Wz[(64+2)*32+c], w3 = Wz[(64+3)*32+c];
    float w4 = Wz[(64+4)*32+c], w5 = Wz[(64+5)*32+c], w6 = Wz[(64+6)*32+c], w7 = Wz[(64+7)*32+c];
    const int d = (blockIdx.x*blockDim.x + threadIdx.x) >> 6;
    if (d >= N_NODES) return;
    const int lo = rowptr[d], hi = rowptr[d+1];
    const float base = AB[(size_t)d*128 + half*64 + c];   // AF_d[c] or AS_d[c]
    float acc = 0.f;
    for (int i = lo; i < hi; i++){
        int s = esrc[i];
        float v = base + AB[(size_t)s*128 + half*64 + 32 + c];  // + BF_s / BS_s
        const float4* ep = (const float4*)(eacsr + (size_t)i*8);
        float4 e0 = ep[0], e1 = ep[1];
        v = fmaf(e0.x, w0, v); v = fmaf(e0.y, w1, v);
        v = fmaf(e0.z, w2, v); v = fmaf(e0.w, w3, v);
        v = fmaf(e1.x, w4, v); v = fmaf(e1.y, w5, v);
        v = fmaf(e1.z, w6, v); v = fmaf(e1.w, w7, v);
        float other = __shfl_xor(v, 32, 64);
        if (half == 0) acc += fast_sigmoid(v) * fast_softplus(other);
    }
    if (half == 0) outp[(size_t)d*32 + c] = fmaxf(xin[(size_t)d*32 + c] + acc, 0.f);
}

// ---------------- GAT ----------------
template<int Ci, int Co>
__global__ void k_linear(const float* __restrict__ in, const float* __restrict__ W,
                         float* __restrict__ out, int N){
    __shared__ float sW[Ci*Co];
    for (int i = threadIdx.x; i < Ci*Co; i += blockDim.x) sW[i] = W[i];
    __syncthreads();
    int idx = blockIdx.x*blockDim.x + threadIdx.x;
    if (idx >= N*Co) return;
    int n = idx / Co, co = idx % Co;
    const float* row = in + (size_t)n*Ci;
    float a = 0.f;
    #pragma unroll
    for (int k = 0; k < Ci; k++) a = fmaf(row[k], sW[k*Co + co], a);
    out[idx] = a;
}

template<int C>
__global__ void k_al(const float* __restrict__ hg, const float* __restrict__ a_src,
                     const float* __restrict__ a_dst,
                     float* __restrict__ als, float* __restrict__ ald){
    int idx = blockIdx.x*blockDim.x + threadIdx.x;
    if (idx >= N_NODES*HEADS) return;
    int n = idx/HEADS, h = idx%HEADS;
    const float* row = hg + ((size_t)n*HEADS + h)*C;
    float as = 0.f, ad = 0.f;
    #pragma unroll
    for (int c = 0; c < C; c++){
        float v = row[c];
        as = fmaf(v, a_src[h*C + c], as);
        ad = fmaf(v, a_dst[h*C + c], ad);
    }
    als[idx] = as; ald[idx] = ad;
}

// Fused GAT per node: 2-pass softmax over CSR edges (+self loop) + weighted
// aggregation + bias + relu. One block per node; thread=(head,channel).
template<int C>
__global__ void k_gat_fused(
    const float* __restrict__ hg, const int* __restrict__ rowptr,
    const int* __restrict__ esrc,
    const float* __restrict__ als, const float* __restrict__ ald,
    const float* __restrict__ bias, float* __restrict__ O)
{
    const int d = blockIdx.x;
    const int tid = threadIdx.x;
    if (tid >= HEADS*C) return;
    const int h = tid / C, c = tid % C;
    const int lo = rowptr[d], hi = rowptr[d+1];
    const float ald_d = ald[d*HEADS + h];
    const float self_logit = lrelu02(als[d*HEADS + h] + ald_d);
    float m = self_logit;
    for (int i = lo; i < hi; i++)
        m = fmaxf(m, lrelu02(als[esrc[i]*HEADS + h] + ald_d));
    float psum = __expf(self_logit - m);
    float acc  = psum * hg[((size_t)d*HEADS + h)*C + c];
    for (int i = lo; i < hi; i++){
        int s = esrc[i];
        float p = __expf(lrelu02(als[s*HEADS + h] + ald_d) - m);
        psum += p;
        acc = fmaf(p, hg[((size_t)s*HEADS + h)*C + c], acc);
    }
    O[((size_t)d*HEADS + h)*C + c] =
        fmaxf(acc*__builtin_amdgcn_rcpf(psum + 1e-16f) + bias[h*C + c], 0.f);
}

// ---------------- pool + MLP ----------------
__global__ __launch_bounds__(256) void k_pool2(
    const float* __restrict__ O2, const int* __restrict__ batch,
    float* __restrict__ gmean){
    __shared__ int s_range[2];
    __shared__ float red[240];
    const int gr = blockIdx.x;
    if (threadIdx.x < 2){
        int key = gr + threadIdx.x;
        int lo = 0, hi = N_NODES;
        while (lo < hi){ int mid = (lo+hi) >> 1; if (batch[mid] < key) lo = mid+1; else hi = mid; }
        s_range[threadIdx.x] = lo;
    }
    __syncthreads();
    const int lo = s_range[0], hi = s_range[1];
    if (threadIdx.x < 240){
        const int c = threadIdx.x % 48, r = threadIdx.x / 48;
        float a = 0.f;
        for (int n = lo + r; n < hi; n += 5) a += O2[(size_t)n*48 + c];
        red[threadIdx.x] = a;
    }
    __syncthreads();
    if (threadIdx.x < 48){
        float a = red[threadIdx.x] + red[48+threadIdx.x] + red[96+threadIdx.x]
                + red[144+threadIdx.x] + red[192+threadIdx.x];
        float cnt = (float)(hi - lo);
        gmean[gr*48 + threadIdx.x] = a / fmaxf(cnt, 1.f);
    }
}

__global__ __launch_bounds__(1024) void k_mlp(
    const float* __restrict__ g,
    const float* __restrict__ Wl1, const float* __restrict__ bl1,
    const float* __restrict__ Wl2, const float* __restrict__ bl2,
    float* __restrict__ out){
    __shared__ float gs[N_GRAPHS*48];
    __shared__ float g1[N_GRAPHS*16];
    int t = threadIdx.x;
    for (int i = t; i < N_GRAPHS*48; i += 1024) gs[i] = g[i];
    __syncthreads();
    if (t < N_GRAPHS*16){
        int n = t/16, j = t%16;
        float a = bl1[j];
        #pragma unroll
        for (int k = 0; k < 48; k++) a = fmaf(gs[n*48 + k], Wl1[k*16 + j], a);
        g1[t] = fmaxf(a, 0.f);
    }
    __syncthreads();
    if (t < N_GRAPHS*10){
        int n = t/10, j = t%10;
        float a = bl2[j];
        #pragma unroll
        for (int k = 0; k < 16; k++) a = fmaf(g1[n*16 + k], Wl2[k*10 + j], a);
        out[n*10 + j] = a;
    }
}

extern "C" void kernel_launch(void* const* d_in, const int* in_sizes, int n_in,
                              void* d_out, int out_size, void* d_ws, size_t ws_size,
                              hipStream_t stream) {
    const float* x    = (const float*)d_in[0];
    const float* ea   = (const float*)d_in[1];
    const int*   ei   = (const int*)  d_in[2];
    const int*   batch= (const int*)  d_in[3];
    const float* Wf1 = (const float*)d_in[4];  const float* bf1 = (const float*)d_in[5];
    const float* Ws1 = (const float*)d_in[6];  const float* bs1 = (const float*)d_in[7];
    const float* Wf2 = (const float*)d_in[8];  const float* bf2 = (const float*)d_in[9];
    const float* Ws2 = (const float*)d_in[10]; const float* bs2 = (const float*)d_in[11];
    const float* Wg1 = (const float*)d_in[12];
    const float* asrc1=(const float*)d_in[13]; const float* adst1=(const float*)d_in[14];
    const float* bg1 = (const float*)d_in[15];
    const float* Wg2 = (const float*)d_in[16];
    const float* asrc2=(const float*)d_in[17]; const float* adst2=(const float*)d_in[18];
    const float* bg2 = (const float*)d_in[19];
    const float* Wl1 = (const float*)d_in[20]; const float* bl1 = (const float*)d_in[21];
    const float* Wl2 = (const float*)d_in[22]; const float* bl2 = (const float*)d_in[23];
    float* out = (float*)d_out;

    const int* srcv = ei;
    const int* dstv = ei + N_EDGES;

    // ---- workspace arena (~68 MB, lifetime overlays) ----
    float* w   = (float*)d_ws;
    float* XA  = w;                  // 1.6M  relu(conv1)
    float* XB  = XA + 1600000;       // 1.6M  relu(conv2) = GAT1 input
    float* R2  = XB + 1600000;       // 6.4M  AB (conv) -> HG1 -> HG2|O2
    float* R3  = R2 + 6400000;       // 6.4M  eacsr (conv) -> O1 (GAT1 out, 4.8M)
    float* ALs = R3 + 6400000;       // 150k
    float* ALd = ALs + 150000;       // 150k
    float* GM  = ALd + 150000;       // 3072
    int* deg    = (int*)(GM + 3072); // 50k
    int* cur    = deg + 50000;       // 50k
    int* rowptr = cur + 50000;       // 50001
    int* esrc   = rowptr + 50001;    // 800k
    float* AB   = R2;
    float* HG1  = R2;
    float* HG2  = R2;
    float* O2   = R2 + 2400000;
    float* eacsr= R3;                // conv phase only
    float* O1   = R3;                // GAT phase only
    (void)ws_size; (void)in_sizes; (void)n_in; (void)out_size;

    auto G = [](int n){ return (n + 255)/256; };

    // ---- CSR by dst (built once; ea permuted into CSR order) ----
    k_zero_i<<<G(N_NODES), 256, 0, stream>>>(deg, N_NODES);
    k_hist<<<G(N_EDGES), 256, 0, stream>>>(dstv, deg);
    k_scan<<<1, 1024, 0, stream>>>(deg, rowptr, cur);
    k_scatter<<<G(N_EDGES), 256, 0, stream>>>(srcv, dstv, ea, cur, esrc, eacsr);

    // ---- CGConv 1 ----
    k_pre<<<G(N_NODES*128), 256, 0, stream>>>(x, Wf1, bf1, Ws1, bs1, AB);
    k_cg_gather<<<(N_NODES*64)/256, 256, 0, stream>>>(x, AB, eacsr, rowptr, esrc, Wf1, Ws1, XA);

    // ---- CGConv 2 ----
    k_pre<<<G(N_NODES*128), 256, 0, stream>>>(XA, Wf2, bf2, Ws2, bs2, AB);
    k_cg_gather<<<(N_NODES*64)/256, 256, 0, stream>>>(XA, AB, eacsr, rowptr, esrc, Wf2, Ws2, XB);

    // ---- GATConv 1 (C=32) ----
    k_linear<32,96><<<G(N_NODES*96), 256, 0, stream>>>(XB, Wg1, HG1, N_NODES);
    k_al<32><<<G(N_NODES*HEADS), 256, 0, stream>>>(HG1, asrc1, adst1, ALs, ALd);
    k_gat_fused<32><<<N_NODES, 128, 0, stream>>>(HG1, rowptr, esrc, ALs, ALd, bg1, O1);

    // ---- GATConv 2 (C=16) ----
    k_linear<96,48><<<G(N_NODES*48), 256, 0, stream>>>(O1, Wg2, HG2, N_NODES);
    k_al<16><<<G(N_NODES*HEADS), 256, 0, stream>>>(HG2, asrc2, adst2, ALs, ALd);
    k_gat_fused<16><<<N_NODES, 64, 0, stream>>>(HG2, rowptr, esrc, ALs, ALd, bg2, O2);

    // ---- pool + MLP ----
    k_pool2<<<N_GRAPHS, 256, 0, stream>>>(O2, batch, GM);
    k_mlp<<<1, 1024, 0, stream>>>(GM, Wl1, bl1, Wl2, bl2, out);
}